// Round 5
// baseline (233.161 us; speedup 1.0000x reference)
//
#include <hip/hip_runtime.h>
#include <hip/hip_bf16.h>

#define B_    4
#define T_    4096
#define D_    2048
#define NTOK  (B_ * T_)
#define NREC  3
#define BAL_W 0.01f
#define Z_W   0.001f

typedef __attribute__((ext_vector_type(4))) float float4v;

// Phase A: one wave per token. logits (3 dots over D=2048) -> softmax/argmax/
// logsumexp in lane 0. d_out is FLOAT32 (49154 elements):
//   [0, NTOK)        : selected        (phase B)
//   [NTOK, 2*NTOK)   : gate, sign bit = inactive tag (uncompacted; fixed by B)
//   [2*NTOK, 3*NTOK) : logit0
//   [3*NTOK] aux, [3*NTOK+1] z
// Loss partials -> accum[4] in d_ws (64 bytes; the only ws use).
__global__ __launch_bounds__(256) void tcr_f32_phaseA(
    const float* __restrict__ x,              // [NTOK, D_] f32
    const float* __restrict__ w,              // [NREC, D_] f32
    const int* __restrict__ ridx_p,
    float* __restrict__ out_f,                // d_out as f32
    float* __restrict__ accum)                // [4]: z2, cnt0, cnt1, cnt2
{
    const int ridx = ridx_p[0];
    const int jc   = ridx < (NREC - 1) ? (ridx < 0 ? 0 : ridx) : (NREC - 1);
    const int lane = threadIdx.x & 63;
    const int wid  = (blockIdx.x * blockDim.x + threadIdx.x) >> 6;
    const int nw   = (gridDim.x * blockDim.x) >> 6;

    // Per-lane W slice in registers: lane owns k = (j*64+lane)*4 .. +4, j=0..7
    float wr[NREC][8][4];
#pragma unroll
    for (int n = 0; n < NREC; ++n)
#pragma unroll
        for (int j = 0; j < 8; ++j) {
            const float4v v = *reinterpret_cast<const float4v*>(w + n * D_ + (j * 64 + lane) * 4);
#pragma unroll
            for (int e = 0; e < 4; ++e) wr[n][j][e] = v[e];
        }

    float z2 = 0.f, c0 = 0.f, c1 = 0.f, c2 = 0.f;

    for (int t = wid; t < NTOK; t += nw) {
        const float* xp = x + (size_t)t * D_;
        float a0 = 0.f, a1 = 0.f, a2 = 0.f;
#pragma unroll
        for (int j = 0; j < 8; ++j) {
            const float4v v = *reinterpret_cast<const float4v*>(xp + (j * 64 + lane) * 4);
#pragma unroll
            for (int e = 0; e < 4; ++e) {
                a0 = fmaf(v[e], wr[0][j][e], a0);
                a1 = fmaf(v[e], wr[1][j][e], a1);
                a2 = fmaf(v[e], wr[2][j][e], a2);
            }
        }
#pragma unroll
        for (int off = 32; off > 0; off >>= 1) {
            a0 += __shfl_xor(a0, off);
            a1 += __shfl_xor(a1, off);
            a2 += __shfl_xor(a2, off);
        }
        if (lane == 0) {
            const float m  = fmaxf(a0, fmaxf(a1, a2));
            const float e0 = expf(a0 - m), e1 = expf(a1 - m), e2 = expf(a2 - m);
            const float s  = e0 + e1 + e2;
            const float z  = m + logf(s);
            int   assign = 0; float best = a0;
            if (a1 > best) { best = a1; assign = 1; }
            if (a2 > best) { best = a2; assign = 2; }
            const float g = (jc == 0 ? e0 : (jc == 1 ? e1 : e2)) / s;   // > 0 strictly

            out_f[NTOK + t]     = (assign >= ridx) ? g : -g;  // sign = inactive tag
            out_f[2 * NTOK + t] = a0;

            z2 += z * z;
            if (assign == 0) c0 += 1.f; else if (assign == 1) c1 += 1.f; else c2 += 1.f;
        }
    }
    if (lane == 0) {
        atomicAdd(accum + 0, z2);
        atomicAdd(accum + 1, c0);
        atomicAdd(accum + 2, c1);
        atomicAdd(accum + 3, c2);
    }
}

// Phase B: per-batch stable compaction (block prefix scan over sign tags)
// + scalar losses. One block per batch; 1024 threads x 4 tokens each.
__global__ __launch_bounds__(1024) void tcr_f32_phaseB(
    const float* __restrict__ accum,
    float* __restrict__ out_f)
{
    __shared__ int      s_sum[1024];
    __shared__ unsigned s_sel[T_];
    __shared__ float    s_g[T_];
    const int b    = blockIdx.x;
    const int tid  = threadIdx.x;
    const int base = b * T_;

    float g[4]; int f[4]; int loc = 0;
#pragma unroll
    for (int r = 0; r < 4; ++r) {
        g[r] = out_f[NTOK + base + tid * 4 + r];
        f[r] = (g[r] > 0.f) ? 1 : 0;       // sign bit set => inactive
        loc += f[r];
    }
    s_sum[tid] = loc;
    __syncthreads();
    // Hillis-Steele inclusive scan (read-barrier-write-barrier: race-free)
    for (int off = 1; off < 1024; off <<= 1) {
        const int v = (tid >= off) ? s_sum[tid - off] : 0;
        __syncthreads();
        s_sum[tid] += v;
        __syncthreads();
    }
    const int cnt = s_sum[1023];
    int pos = s_sum[tid] - loc;            // exclusive prefix for this thread
#pragma unroll
    for (int r = 0; r < 4; ++r) {
        if (f[r] && (unsigned)pos < (unsigned)T_) {
            s_sel[pos] = (unsigned)(tid * 4 + r);
            s_g[pos]   = g[r];
            ++pos;
        }
    }
    __syncthreads();

#pragma unroll
    for (int r = 0; r < 4; ++r) {
        const int k = tid + r * 1024;      // coalesced
        float selv, gv;
        if (cnt == 0) { selv = 0.f; gv = 0.f; }
        else {
            const int kk = (k < cnt) ? k : (cnt - 1);
            selv = (float)s_sel[kk];
            gv   = s_g[kk];
        }
        out_f[base + k]        = selv;     // selected
        out_f[NTOK + base + k] = gv;       // gate_weights (compacted)
    }

    if (b == 0 && tid == 0) {
        const float inv = 1.0f / (float)NTOK;
        float aux = 0.f;
#pragma unroll
        for (int n = 0; n < NREC; ++n) {
            const float d = accum[1 + n] * inv - (1.0f / 3.0f);
            aux = fmaf(d, d, aux);
        }
        out_f[3 * NTOK + 0] = BAL_W * aux;
        out_f[3 * NTOK + 1] = Z_W * accum[0] * inv;
    }
}

extern "C" void kernel_launch(void* const* d_in, const int* in_sizes, int n_in,
                              void* d_out, int out_size, void* d_ws, size_t ws_size,
                              hipStream_t stream) {
    const float* x  = (const float*)d_in[0];
    const float* w  = (const float*)d_in[1];
    const int* ridx = (const int*)d_in[2];
    float* out_f = (float*)d_out;
    float* accum = (float*)d_ws;   // 64 bytes of ws only

    hipMemsetAsync(d_ws, 0, 64, stream);
    tcr_f32_phaseA<<<dim3(1024), dim3(256), 0, stream>>>(x, w, ridx, out_f, accum);
    tcr_f32_phaseB<<<dim3(B_), dim3(1024), 0, stream>>>(accum, out_f);
}

// Round 6
// 32.884 us; speedup vs baseline: 7.0905x; 7.0905x over previous
//
#include <hip/hip_runtime.h>
#include <hip/hip_bf16.h>

#define B_    4
#define T_    4096
#define D_    2048
#define NTOK  (B_ * T_)
#define NREC  3
#define BAL_W 0.01f
#define Z_W   0.001f
#define NBLK  1024   // phaseA grid; partials array = NBLK float4 in d_ws

typedef __attribute__((ext_vector_type(4))) float float4v;

// Phase A: one wave per token. logits (3 dots over D=2048) -> softmax/argmax/
// logsumexp in lane 0. d_out is FLOAT32 (49154 elements):
//   [0, NTOK)        : selected        (written by phase B)
//   [NTOK, 2*NTOK)   : gate, sign bit = inactive tag (uncompacted; fixed by B)
//   [2*NTOK, 3*NTOK) : logit0
//   [3*NTOK] aux, [3*NTOK+1] z
// Loss partials: NO atomics — block-level LDS reduce, one float4 per block
// into d_ws (z2, cnt0, cnt1, cnt2).
__global__ __launch_bounds__(256) void tcr_f32_phaseA(
    const float* __restrict__ x,              // [NTOK, D_] f32
    const float* __restrict__ w,              // [NREC, D_] f32
    const int* __restrict__ ridx_p,
    float* __restrict__ out_f,                // d_out as f32
    float4v* __restrict__ partials)           // [NBLK] in d_ws
{
    const int ridx = ridx_p[0];
    const int jc   = ridx < (NREC - 1) ? (ridx < 0 ? 0 : ridx) : (NREC - 1);
    const int lane = threadIdx.x & 63;
    const int wv   = threadIdx.x >> 6;        // wave within block (0..3)
    const int wid  = (blockIdx.x * blockDim.x + threadIdx.x) >> 6;
    const int nw   = (gridDim.x * blockDim.x) >> 6;

    // Per-lane W slice in registers: lane owns k = (j*64+lane)*4 .. +4, j=0..7
    float wr[NREC][8][4];
#pragma unroll
    for (int n = 0; n < NREC; ++n)
#pragma unroll
        for (int j = 0; j < 8; ++j) {
            const float4v v = *reinterpret_cast<const float4v*>(w + n * D_ + (j * 64 + lane) * 4);
#pragma unroll
            for (int e = 0; e < 4; ++e) wr[n][j][e] = v[e];
        }

    float z2 = 0.f, c0 = 0.f, c1 = 0.f, c2 = 0.f;

    for (int t = wid; t < NTOK; t += nw) {
        const float* xp = x + (size_t)t * D_;
        float a0 = 0.f, a1 = 0.f, a2 = 0.f;
#pragma unroll
        for (int j = 0; j < 8; ++j) {
            const float4v v = *reinterpret_cast<const float4v*>(xp + (j * 64 + lane) * 4);
#pragma unroll
            for (int e = 0; e < 4; ++e) {
                a0 = fmaf(v[e], wr[0][j][e], a0);
                a1 = fmaf(v[e], wr[1][j][e], a1);
                a2 = fmaf(v[e], wr[2][j][e], a2);
            }
        }
#pragma unroll
        for (int off = 32; off > 0; off >>= 1) {
            a0 += __shfl_xor(a0, off);
            a1 += __shfl_xor(a1, off);
            a2 += __shfl_xor(a2, off);
        }
        if (lane == 0) {
            const float m  = fmaxf(a0, fmaxf(a1, a2));
            const float e0 = expf(a0 - m), e1 = expf(a1 - m), e2 = expf(a2 - m);
            const float s  = e0 + e1 + e2;
            const float z  = m + logf(s);
            int   assign = 0; float best = a0;
            if (a1 > best) { best = a1; assign = 1; }
            if (a2 > best) { best = a2; assign = 2; }
            const float g = (jc == 0 ? e0 : (jc == 1 ? e1 : e2)) / s;   // > 0 strictly

            out_f[NTOK + t]     = (assign >= ridx) ? g : -g;  // sign = inactive tag
            out_f[2 * NTOK + t] = a0;

            z2 += z * z;
            if (assign == 0) c0 += 1.f; else if (assign == 1) c1 += 1.f; else c2 += 1.f;
        }
    }

    // Block-level partial reduce (4 waves) -> one float4 store per block.
    __shared__ float4v s_part[4];
    if (lane == 0) {
        float4v p; p[0] = z2; p[1] = c0; p[2] = c1; p[3] = c2;
        s_part[wv] = p;
    }
    __syncthreads();
    if (threadIdx.x == 0) {
        float4v p = s_part[0];
#pragma unroll
        for (int i = 1; i < 4; ++i) {
            const float4v q = s_part[i];
#pragma unroll
            for (int e = 0; e < 4; ++e) p[e] += q[e];
        }
        partials[blockIdx.x] = p;
    }
}

// Phase B: per-batch stable compaction (block prefix scan over sign tags);
// block 0 additionally tree-reduces the NBLK loss partials and writes aux/z.
__global__ __launch_bounds__(1024) void tcr_f32_phaseB(
    const float4v* __restrict__ partials,
    float* __restrict__ out_f)
{
    __shared__ int      s_sum[1024];
    __shared__ unsigned s_sel[T_];
    __shared__ float    s_g[T_];
    __shared__ float4v  s_red[1024];
    const int b    = blockIdx.x;
    const int tid  = threadIdx.x;
    const int base = b * T_;

    float g[4]; int f[4]; int loc = 0;
#pragma unroll
    for (int r = 0; r < 4; ++r) {
        g[r] = out_f[NTOK + base + tid * 4 + r];
        f[r] = (g[r] > 0.f) ? 1 : 0;       // sign bit set => inactive
        loc += f[r];
    }
    s_sum[tid] = loc;
    __syncthreads();
    // Hillis-Steele inclusive scan (read-barrier-write-barrier: race-free)
    for (int off = 1; off < 1024; off <<= 1) {
        const int v = (tid >= off) ? s_sum[tid - off] : 0;
        __syncthreads();
        s_sum[tid] += v;
        __syncthreads();
    }
    const int cnt = s_sum[1023];
    int pos = s_sum[tid] - loc;            // exclusive prefix for this thread
#pragma unroll
    for (int r = 0; r < 4; ++r) {
        if (f[r] && (unsigned)pos < (unsigned)T_) {
            s_sel[pos] = (unsigned)(tid * 4 + r);
            s_g[pos]   = g[r];
            ++pos;
        }
    }
    __syncthreads();

#pragma unroll
    for (int r = 0; r < 4; ++r) {
        const int k = tid + r * 1024;      // coalesced
        float selv, gv;
        if (cnt == 0) { selv = 0.f; gv = 0.f; }
        else {
            const int kk = (k < cnt) ? k : (cnt - 1);
            selv = (float)s_sel[kk];
            gv   = s_g[kk];
        }
        out_f[base + k]        = selv;     // selected
        out_f[NTOK + base + k] = gv;       // gate_weights (compacted)
    }

    // Loss reduction: only block 0 (uniform barriers within the block).
    if (b == 0) {
        s_red[tid] = partials[tid];        // NBLK == 1024
        __syncthreads();
        for (int off = 512; off > 0; off >>= 1) {
            if (tid < off) {
                float4v a = s_red[tid], c = s_red[tid + off];
#pragma unroll
                for (int e = 0; e < 4; ++e) a[e] += c[e];
                s_red[tid] = a;
            }
            __syncthreads();
        }
        if (tid == 0) {
            const float4v p = s_red[0];
            const float inv = 1.0f / (float)NTOK;
            float aux = 0.f;
#pragma unroll
            for (int n = 0; n < NREC; ++n) {
                const float d = p[1 + n] * inv - (1.0f / 3.0f);
                aux = fmaf(d, d, aux);
            }
            out_f[3 * NTOK + 0] = BAL_W * aux;
            out_f[3 * NTOK + 1] = Z_W * p[0] * inv;
        }
    }
}

extern "C" void kernel_launch(void* const* d_in, const int* in_sizes, int n_in,
                              void* d_out, int out_size, void* d_ws, size_t ws_size,
                              hipStream_t stream) {
    const float* x  = (const float*)d_in[0];
    const float* w  = (const float*)d_in[1];
    const int* ridx = (const int*)d_in[2];
    float* out_f = (float*)d_out;
    float4v* partials = (float4v*)d_ws;   // 16 KB of ws

    tcr_f32_phaseA<<<dim3(NBLK), dim3(256), 0, stream>>>(x, w, ridx, out_f, partials);
    tcr_f32_phaseB<<<dim3(B_), dim3(1024), 0, stream>>>(partials, out_f);
}